// Round 4
// baseline (561.084 us; speedup 1.0000x reference)
//
#include <hip/hip_runtime.h>
#include <hip/hip_bf16.h>
#include <hip/hip_cooperative_groups.h>
#include <cstdint>

// MFVI second-order CRF, B=32 S=1024 T=256 W=2 ITER=3.
// msg = Shift(P) @ Wc, M=32768 N=256 K=1024 (4 shift regions).
// Round 4: LDS slimmed to 19.5 KB (B read direct from L2 -> no per-phase
// barriers; 64KB-accounting occupancy = 3 blocks/CU so the 512-block coop
// grid is valid). Coop launch return code checked, multi-kernel fallback.
//
// ws: Pa bf16 [32][1028][256] @0 | Pb @32MB | WcT bf16 [256][1024] @64MB

namespace cg = cooperative_groups;

typedef __attribute__((ext_vector_type(4))) float f32x4;
typedef __attribute__((ext_vector_type(8))) short bf16x8;

__device__ __forceinline__ void load_lds16(const void* g, void* l) {
    __builtin_amdgcn_global_load_lds(
        (const __attribute__((address_space(1))) void*)g,
        (__attribute__((address_space(3))) void*)l, 16, 0, 0);
}

// One 64-row M-tile: GEMM over K=1024 (P-slice staged once per 128-col half,
// XOR-swizzled; B-fragments straight from L2), fused boundary+unary+mask,
// then row-softmax -> Pout (bf16) or final fp32 -> out.
__device__ __forceinline__ void do_tile(
    int tile, const __hip_bfloat16* __restrict__ Pin,
    const __hip_bfloat16* __restrict__ WcT,
    const float* __restrict__ unary, const int* __restrict__ lengths,
    const float* __restrict__ startT, const float* __restrict__ endT,
    __hip_bfloat16* __restrict__ Pout, float* __restrict__ out, int final_it,
    __hip_bfloat16* Ps, float* redA, float* redB)
{
    int tid = threadIdx.x;
    int lane = tid & 63, wid = tid >> 6;
    int cn = lane & 15, quad = lane >> 4, wn = wid << 6;
    int b = tile >> 4, s0 = (tile & 15) << 6;
    int len = lengths[b];
    const char* Pbase = (const char*)(Pin + ((size_t)b * 1028 + s0) * 256);

    f32x4 acc[4][4] = {};

    for (int h = 0; h < 2; ++h) {
        // stage P rows s0-2..s0+65 (padded rows s0..s0+67), cols h*128..+127.
        // LDS slot c=row*16+ch holds global chunk (ch&~7)|((ch^row)&7).
        #pragma unroll
        for (int t = 0; t < 5; ++t) {
            int c = t * 256 + tid;
            if (t < 4 || tid < 64) {
                int row = c >> 4, ch = c & 15;
                int gch = (ch & ~7) | ((ch ^ row) & 7);
                load_lds16(Pbase + row * 512 + h * 256 + gch * 16,
                           (char*)Ps + c * 16);
            }
        }
        __syncthreads();

        #pragma unroll 2
        for (int p = 0; p < 8; ++p) {
            int region = p >> 1;
            int delta = (region == 0) ? -1 : (region == 1) ? -2
                      : (region == 2) ?  1 : 2;
            const __hip_bfloat16* Bk = WcT + region * 256 + h * 128 + (p & 1) * 64;
            #pragma unroll
            for (int kk = 0; kk < 2; ++kk) {
                bf16x8 af[4], bfv[4];
                #pragma unroll
                for (int j = 0; j < 4; ++j)
                    bfv[j] = *(const bf16x8*)(
                        Bk + (size_t)(wn + (j << 4) + cn) * 1024 + kk * 32 + quad * 8);
                int gcb = (p & 1) * 8 + kk * 4 + quad;   // chunk within 128-half
                #pragma unroll
                for (int i = 0; i < 4; ++i) {
                    int r = (i << 4) + cn + delta + 2;   // 0..67
                    int slot = (gcb & ~7) | ((gcb ^ r) & 7);
                    af[i] = *(const bf16x8*)((const char*)Ps + r * 256 + slot * 16);
                }
                #pragma unroll
                for (int i = 0; i < 4; ++i)
                    #pragma unroll
                    for (int j = 0; j < 4; ++j)
                        acc[i][j] = __builtin_amdgcn_mfma_f32_16x16x32_bf16(
                            af[i], bfv[j], acc[i][j], 0, 0, 0);
            }
        }
        __syncthreads();
    }

    // boundary + unary + mask. C/D: col=lane&15, row=quad*4+reg
    #pragma unroll
    for (int i = 0; i < 4; ++i)
        #pragma unroll
        for (int j = 0; j < 4; ++j) {
            int n = wn + (j << 4) + cn;
            #pragma unroll
            for (int r = 0; r < 4; ++r) {
                int s = s0 + (i << 4) + (quad << 2) + r;
                float x = acc[i][j][r];
                if (s == 0)       x += startT[n];
                if (s == 1)       x += startT[256 + n];
                if (s == len - 1) x += endT[n];
                if (s == len - 2) x += endT[256 + n];
                long idx = ((long)((b << 10) + s)) * 256 + n;
                x += unary[idx];
                acc[i][j][r] = (s < len) ? x : 0.f;
            }
        }

    if (final_it) {
        #pragma unroll
        for (int i = 0; i < 4; ++i)
            #pragma unroll
            for (int j = 0; j < 4; ++j) {
                int n = wn + (j << 4) + cn;
                #pragma unroll
                for (int r = 0; r < 4; ++r) {
                    int s = s0 + (i << 4) + (quad << 2) + r;
                    out[((long)((b << 10) + s)) * 256 + n] = acc[i][j][r];
                }
            }
        return;
    }

    // fused row softmax over 256 cols
    #pragma unroll
    for (int i = 0; i < 4; ++i)
        #pragma unroll
        for (int r = 0; r < 4; ++r) {
            float m4 = fmaxf(fmaxf(acc[i][0][r], acc[i][1][r]),
                             fmaxf(acc[i][2][r], acc[i][3][r]));
            m4 = fmaxf(m4, __shfl_xor(m4, 1));
            m4 = fmaxf(m4, __shfl_xor(m4, 2));
            m4 = fmaxf(m4, __shfl_xor(m4, 4));
            m4 = fmaxf(m4, __shfl_xor(m4, 8));
            if (cn == 0) redA[(wid << 6) + (i << 4) + (quad << 2) + r] = m4;
        }
    __syncthreads();
    float M[4][4];
    #pragma unroll
    for (int i = 0; i < 4; ++i)
        #pragma unroll
        for (int r = 0; r < 4; ++r) {
            int row = (i << 4) + (quad << 2) + r;
            M[i][r] = fmaxf(fmaxf(redA[row], redA[64 + row]),
                            fmaxf(redA[128 + row], redA[192 + row]));
        }
    #pragma unroll
    for (int i = 0; i < 4; ++i)
        #pragma unroll
        for (int r = 0; r < 4; ++r) {
            float s4 = 0.f;
            #pragma unroll
            for (int j = 0; j < 4; ++j) {
                float e = __expf(acc[i][j][r] - M[i][r]);
                acc[i][j][r] = e;
                s4 += e;
            }
            s4 += __shfl_xor(s4, 1);
            s4 += __shfl_xor(s4, 2);
            s4 += __shfl_xor(s4, 4);
            s4 += __shfl_xor(s4, 8);
            if (cn == 0) redB[(wid << 6) + (i << 4) + (quad << 2) + r] = s4;
        }
    __syncthreads();
    #pragma unroll
    for (int i = 0; i < 4; ++i)
        #pragma unroll
        for (int r = 0; r < 4; ++r) {
            int row = (i << 4) + (quad << 2) + r;
            float inv = 1.0f / (redB[row] + redB[64 + row] +
                                redB[128 + row] + redB[192 + row]);
            int s = s0 + row;
            #pragma unroll
            for (int j = 0; j < 4; ++j) {
                int n = wn + (j << 4) + cn;
                Pout[((size_t)b * 1028 + 2 + s) * 256 + n] =
                    __float2bfloat16(acc[i][j][r] * inv);
            }
        }
}

// ---------------- phase-0 helpers (shared logic) ---------------------------
__device__ __forceinline__ void wct_one(const float* __restrict__ trans,
                                        __hip_bfloat16* __restrict__ wct, int e) {
    int n = e >> 10, k = e & 1023;
    int r = k >> 8, kk = k & 255;
    float v;
    if (r == 0)      v = trans[kk * 256 + n];
    else if (r == 1) v = trans[65536 + kk * 256 + n];
    else if (r == 2) v = trans[n * 256 + kk];
    else             v = trans[65536 + n * 256 + kk];
    wct[n * 1024 + k] = __float2bfloat16(v);
}

__device__ __forceinline__ void guard_one(__hip_bfloat16* Pa, __hip_bfloat16* Pb, int g) {
    __hip_bfloat16* P = (g & 32768) ? Pb : Pa;
    int rem = g & 32767;
    int b = rem >> 10, wr = (rem >> 8) & 3, col = rem & 255;
    int row = b * 1028 + ((wr < 2) ? wr : 1024 + wr);   // 0,1,1026,1027
    P[row * 256 + col] = __float2bfloat16(0.f);
}

__device__ __forceinline__ void softmax0_row(const float* __restrict__ unary,
                                             const int* __restrict__ lengths,
                                             __hip_bfloat16* __restrict__ Pa,
                                             int row, int lane) {
    int b = row >> 10, s = row & 1023;
    float mval = (s < lengths[b]) ? 1.f : 0.f;
    float4 x = *((const float4*)(unary + (size_t)row * 256 + lane * 4));
    x.x *= mval; x.y *= mval; x.z *= mval; x.w *= mval;
    float mx = fmaxf(fmaxf(x.x, x.y), fmaxf(x.z, x.w));
    #pragma unroll
    for (int o = 32; o; o >>= 1) mx = fmaxf(mx, __shfl_xor(mx, o));
    float ea = __expf(x.x - mx), eb = __expf(x.y - mx);
    float ec = __expf(x.z - mx), ed = __expf(x.w - mx);
    float sum = ea + eb + ec + ed;
    #pragma unroll
    for (int o = 32; o; o >>= 1) sum += __shfl_xor(sum, o);
    float inv = 1.0f / sum;
    union { ushort4 u; __hip_bfloat16 h[4]; } o4;
    o4.h[0] = __float2bfloat16(ea * inv);
    o4.h[1] = __float2bfloat16(eb * inv);
    o4.h[2] = __float2bfloat16(ec * inv);
    o4.h[3] = __float2bfloat16(ed * inv);
    *((ushort4*)(Pa + ((size_t)b * 1028 + 2 + s) * 256 + lane * 4)) = o4.u;
}

// ---------------- cooperative single kernel --------------------------------
__global__ __launch_bounds__(256, 2) void mfvi_coop(
    const float* __restrict__ unary, const float* __restrict__ trans,
    const float* __restrict__ startT, const float* __restrict__ endT,
    const int* __restrict__ lengths,
    __hip_bfloat16* __restrict__ Pa, __hip_bfloat16* __restrict__ Pb,
    __hip_bfloat16* __restrict__ WcT, float* __restrict__ out)
{
    cg::grid_group grid = cg::this_grid();
    __shared__ __hip_bfloat16 Ps[68 * 128];   // 17408 B
    __shared__ float redA[256];
    __shared__ float redB[256];

    int tid = threadIdx.x, lane = tid & 63, wid = tid >> 6;
    int blk = blockIdx.x;                      // 0..511

    // phase 0: WcT build + guard zero + softmax0
    {
        int e0 = (blk * 256 + tid) * 2;
        wct_one(trans, WcT, e0);
        wct_one(trans, WcT, e0 + 1);
        if (blk >= 256 && blk < 384) {
            int g0 = ((blk - 256) * 256 + tid) * 2;
            guard_one(Pa, Pb, g0);
            guard_one(Pa, Pb, g0 + 1);
        }
        for (int q = 0; q < 16; ++q)
            softmax0_row(unary, lengths, Pa, blk * 64 + wid * 16 + q, lane);
    }
    grid.sync();

    do_tile(blk, Pa, WcT, unary, lengths, startT, endT, Pb, nullptr, 0,
            Ps, redA, redB);
    grid.sync();
    do_tile(blk, Pb, WcT, unary, lengths, startT, endT, Pa, nullptr, 0,
            Ps, redA, redB);
    grid.sync();
    do_tile(blk, Pa, WcT, unary, lengths, startT, endT, nullptr, out, 1,
            Ps, redA, redB);
}

// ---------------- fallback path (4 dispatches) -----------------------------
__global__ __launch_bounds__(256) void prep_softmax0(
    const float* __restrict__ unary, const float* __restrict__ trans,
    const int* __restrict__ lengths,
    __hip_bfloat16* __restrict__ Pa, __hip_bfloat16* __restrict__ Pb,
    __hip_bfloat16* __restrict__ WcT)
{
    int tid = threadIdx.x, lane = tid & 63, wid = tid >> 6;
    int blk = blockIdx.x;                      // 0..511
    int e0 = (blk * 256 + tid) * 2;
    wct_one(trans, WcT, e0);
    wct_one(trans, WcT, e0 + 1);
    int idx = blk * 256 + tid;
    if (idx < 65536) guard_one(Pa, Pb, idx);
    else             guard_one(Pa, Pb, idx - 65536);
    for (int q = 0; q < 16; ++q)
        softmax0_row(unary, lengths, Pa, blk * 64 + wid * 16 + q, lane);
}

__global__ __launch_bounds__(256, 2) void mfvi_iter_k(
    const __hip_bfloat16* __restrict__ Pin,
    const __hip_bfloat16* __restrict__ WcT,
    const float* __restrict__ unary, const int* __restrict__ lengths,
    const float* __restrict__ startT, const float* __restrict__ endT,
    __hip_bfloat16* __restrict__ Pout, float* __restrict__ out, int final_it)
{
    __shared__ __hip_bfloat16 Ps[68 * 128];
    __shared__ float redA[256];
    __shared__ float redB[256];
    do_tile(blockIdx.x, Pin, WcT, unary, lengths, startT, endT, Pout, out,
            final_it, Ps, redA, redB);
}

extern "C" void kernel_launch(void* const* d_in, const int* in_sizes, int n_in,
                              void* d_out, int out_size, void* d_ws, size_t ws_size,
                              hipStream_t stream) {
    const float* unary  = (const float*)d_in[1];
    const float* trans  = (const float*)d_in[3];
    const float* startT = (const float*)d_in[4];
    const float* endT   = (const float*)d_in[5];
    const int*   lens   = (const int*)d_in[6];

    char* ws = (char*)d_ws;
    __hip_bfloat16* Pa  = (__hip_bfloat16*)ws;                          // 16.8 MB
    __hip_bfloat16* Pb  = (__hip_bfloat16*)(ws + ((size_t)32 << 20));   // 16.8 MB
    __hip_bfloat16* WcT = (__hip_bfloat16*)(ws + ((size_t)64 << 20));   // 512 KB
    float* out = (float*)d_out;

    void* args[] = { (void*)&unary, (void*)&trans, (void*)&startT, (void*)&endT,
                     (void*)&lens, (void*)&Pa, (void*)&Pb, (void*)&WcT, (void*)&out };
    hipError_t err = hipLaunchCooperativeKernel((const void*)mfvi_coop,
                                                dim3(512), dim3(256),
                                                args, 0, stream);
    if (err != hipSuccess) {
        (void)hipGetLastError();   // clear sticky error, use fallback path
        prep_softmax0<<<dim3(512), dim3(256), 0, stream>>>(unary, trans, lens, Pa, Pb, WcT);
        mfvi_iter_k<<<dim3(512), dim3(256), 0, stream>>>(Pa, WcT, unary, lens, startT, endT, Pb, nullptr, 0);
        mfvi_iter_k<<<dim3(512), dim3(256), 0, stream>>>(Pb, WcT, unary, lens, startT, endT, Pa, nullptr, 0);
        mfvi_iter_k<<<dim3(512), dim3(256), 0, stream>>>(Pa, WcT, unary, lens, startT, endT, nullptr, out, 1);
    }
}

// Round 5
// 286.862 us; speedup vs baseline: 1.9559x; 1.9559x over previous
//
#include <hip/hip_runtime.h>
#include <hip/hip_bf16.h>
#include <cstdint>

// MFVI second-order CRF, B=32 S=1024 T=256 W=2 ITER=3.
// msg = Shift(P) @ Wc, M=32768 N=256 K=1024 (4 shift regions).
// Round 5: plain launches (coop replay cost 188us). Round-2 coalesced
// global_load_lds B-staging + Ps resident per column-half + 512-thread
// blocks (8 waves, 16 waves/CU = 2x occupancy for latency hiding).
//
// ws: Pa bf16 [32][1028][256] @0 | Pb @32MB | WcT bf16 [256][1024] @64MB

typedef __attribute__((ext_vector_type(4))) float f32x4;
typedef __attribute__((ext_vector_type(8))) short bf16x8;

__device__ __forceinline__ void load_lds16(const void* g, void* l) {
    __builtin_amdgcn_global_load_lds(
        (const __attribute__((address_space(1))) void*)g,
        (__attribute__((address_space(3))) void*)l, 16, 0, 0);
}

// ---------------- phase-0 helpers ------------------------------------------
__device__ __forceinline__ void wct_one(const float* __restrict__ trans,
                                        __hip_bfloat16* __restrict__ wct, int e) {
    int n = e >> 10, k = e & 1023;
    int r = k >> 8, kk = k & 255;
    float v;
    if (r == 0)      v = trans[kk * 256 + n];
    else if (r == 1) v = trans[65536 + kk * 256 + n];
    else if (r == 2) v = trans[n * 256 + kk];
    else             v = trans[65536 + n * 256 + kk];
    wct[n * 1024 + k] = __float2bfloat16(v);
}

__device__ __forceinline__ void guard_one(__hip_bfloat16* Pa, __hip_bfloat16* Pb, int g) {
    __hip_bfloat16* P = (g & 32768) ? Pb : Pa;
    int rem = g & 32767;
    int b = rem >> 10, wr = (rem >> 8) & 3, col = rem & 255;
    int row = b * 1028 + ((wr < 2) ? wr : 1024 + wr);   // 0,1,1026,1027
    P[row * 256 + col] = __float2bfloat16(0.f);
}

__device__ __forceinline__ void softmax0_row(const float* __restrict__ unary,
                                             const int* __restrict__ lengths,
                                             __hip_bfloat16* __restrict__ Pa,
                                             int row, int lane) {
    int b = row >> 10, s = row & 1023;
    float mval = (s < lengths[b]) ? 1.f : 0.f;
    float4 x = *((const float4*)(unary + (size_t)row * 256 + lane * 4));
    x.x *= mval; x.y *= mval; x.z *= mval; x.w *= mval;
    float mx = fmaxf(fmaxf(x.x, x.y), fmaxf(x.z, x.w));
    #pragma unroll
    for (int o = 32; o; o >>= 1) mx = fmaxf(mx, __shfl_xor(mx, o));
    float ea = __expf(x.x - mx), eb = __expf(x.y - mx);
    float ec = __expf(x.z - mx), ed = __expf(x.w - mx);
    float sum = ea + eb + ec + ed;
    #pragma unroll
    for (int o = 32; o; o >>= 1) sum += __shfl_xor(sum, o);
    float inv = 1.0f / sum;
    union { ushort4 u; __hip_bfloat16 h[4]; } o4;
    o4.h[0] = __float2bfloat16(ea * inv);
    o4.h[1] = __float2bfloat16(eb * inv);
    o4.h[2] = __float2bfloat16(ec * inv);
    o4.h[3] = __float2bfloat16(ed * inv);
    *((ushort4*)(Pa + ((size_t)b * 1028 + 2 + s) * 256 + lane * 4)) = o4.u;
}

__global__ __launch_bounds__(256) void prep_softmax0(
    const float* __restrict__ unary, const float* __restrict__ trans,
    const int* __restrict__ lengths,
    __hip_bfloat16* __restrict__ Pa, __hip_bfloat16* __restrict__ Pb,
    __hip_bfloat16* __restrict__ WcT)
{
    int tid = threadIdx.x, lane = tid & 63, wid = tid >> 6;
    int blk = blockIdx.x;                      // 0..511
    int e0 = (blk * 256 + tid) * 2;
    wct_one(trans, WcT, e0);
    wct_one(trans, WcT, e0 + 1);
    int idx = blk * 256 + tid;
    if (idx < 65536) guard_one(Pa, Pb, idx);
    for (int q = 0; q < 16; ++q)
        softmax0_row(unary, lengths, Pa, blk * 64 + wid * 16 + q, lane);
}

// ---------------- iteration kernel -----------------------------------------
// Block: 512 threads = 8 waves. M-tile 64 x N 256. Wave w: rows (w>>2)*32..+31,
// cols (w&3)*64..+63. Ps (A) staged once per 128-col half; Bs (WcT 64-k slice)
// staged per p-step via global_load_lds DMA.
__global__ __launch_bounds__(512, 4) void mfvi_iter_k(
    const __hip_bfloat16* __restrict__ Pin,   // [32][1028][256] padded
    const __hip_bfloat16* __restrict__ WcT,   // [256][1024]
    const float* __restrict__ unary, const int* __restrict__ lengths,
    const float* __restrict__ startT, const float* __restrict__ endT,
    __hip_bfloat16* __restrict__ Pout, float* __restrict__ out, int final_it)
{
    __shared__ __hip_bfloat16 Ps[68 * 128];   // 17408 B
    __shared__ __hip_bfloat16 Bs[256 * 64];   // 32768 B
    __shared__ float redA[256];               // [nslice][row]
    __shared__ float redB[256];

    int tid = threadIdx.x;
    int lane = tid & 63, w = tid >> 6;
    int cn = lane & 15, quad = lane >> 4;
    int wm = (w >> 2) * 32, wn = (w & 3) * 64;
    int nslice = w & 3;
    int tile = blockIdx.x;
    int b = tile >> 4, s0 = (tile & 15) << 6;
    int len = lengths[b];
    const char* Pbase = (const char*)(Pin + ((size_t)b * 1028 + s0) * 256);

    f32x4 acc[2][4] = {};

    int sr = tid >> 3, sc = tid & 7;          // Bs staging coords

    for (int h = 0; h < 2; ++h) {
        // stage Ps: rows s0-2..s0+65 (padded rows s0..s0+67), cols h*128..+127
        // 1088 x 16B chunks; LDS slot c=row*16+ch holds chunk (ch&~7)|((ch^row)&7)
        #pragma unroll
        for (int t = 0; t < 3; ++t) {
            int c = t * 512 + tid;
            if (t < 2 || tid < 64) {
                int row = c >> 4, ch = c & 15;
                int gch = (ch & ~7) | ((ch ^ row) & 7);
                load_lds16(Pbase + row * 512 + h * 256 + gch * 16,
                           (char*)Ps + c * 16);
            }
        }
        for (int p = 0; p < 8; ++p) {
            int region = p >> 1;
            int delta = (region == 0) ? -1 : (region == 1) ? -2
                      : (region == 2) ?  1 : 2;
            int k0 = region * 256 + h * 128 + (p & 1) * 64;

            // stage Bs: 256 rows x 64 k, 2048 chunks, 4/thread (coalesced DMA)
            #pragma unroll
            for (int c = 0; c < 4; ++c) {
                int n = c * 64 + sr;
                load_lds16((const char*)(WcT + n * 1024 + k0) + ((sc ^ (n & 7)) << 4),
                           (char*)Bs + c * 8192 + tid * 16);
            }
            __syncthreads();

            #pragma unroll
            for (int kk = 0; kk < 2; ++kk) {
                bf16x8 af[2], bfv[4];
                int gcb = (p & 1) * 8 + kk * 4 + quad;   // Ps chunk in 128-half
                #pragma unroll
                for (int i = 0; i < 2; ++i) {
                    int r = wm + (i << 4) + cn + delta + 2;   // 0..67
                    int slot = (gcb & ~7) | ((gcb ^ r) & 7);
                    af[i] = *(const bf16x8*)((const char*)Ps + r * 256 + slot * 16);
                }
                int qb = kk * 4 + quad;                  // Bs chunk 0..7
                #pragma unroll
                for (int j = 0; j < 4; ++j) {
                    int n = wn + (j << 4) + cn;
                    bfv[j] = *(const bf16x8*)((char*)Bs + n * 128 + ((qb ^ (n & 7)) << 4));
                }
                #pragma unroll
                for (int i = 0; i < 2; ++i)
                    #pragma unroll
                    for (int j = 0; j < 4; ++j)
                        acc[i][j] = __builtin_amdgcn_mfma_f32_16x16x32_bf16(
                            af[i], bfv[j], acc[i][j], 0, 0, 0);
            }
            __syncthreads();
        }
    }

    // boundary + unary + mask. C/D: col=lane&15, row=quad*4+reg
    #pragma unroll
    for (int i = 0; i < 2; ++i)
        #pragma unroll
        for (int j = 0; j < 4; ++j) {
            int n = wn + (j << 4) + cn;
            #pragma unroll
            for (int r = 0; r < 4; ++r) {
                int s = s0 + wm + (i << 4) + (quad << 2) + r;
                float x = acc[i][j][r];
                if (s == 0)       x += startT[n];
                if (s == 1)       x += startT[256 + n];
                if (s == len - 1) x += endT[n];
                if (s == len - 2) x += endT[256 + n];
                long idx = ((long)((b << 10) + s)) * 256 + n;
                x += unary[idx];
                acc[i][j][r] = (s < len) ? x : 0.f;
            }
        }

    if (final_it) {
        #pragma unroll
        for (int i = 0; i < 2; ++i)
            #pragma unroll
            for (int j = 0; j < 4; ++j) {
                int n = wn + (j << 4) + cn;
                #pragma unroll
                for (int r = 0; r < 4; ++r) {
                    int s = s0 + wm + (i << 4) + (quad << 2) + r;
                    out[((long)((b << 10) + s)) * 256 + n] = acc[i][j][r];
                }
            }
        return;
    }

    // fused row softmax over 256 cols: quad shfl-reduce, then combine the
    // 4 N-slices via LDS. redA[nslice][row(0..63)]
    #pragma unroll
    for (int i = 0; i < 2; ++i)
        #pragma unroll
        for (int r = 0; r < 4; ++r) {
            float m4 = fmaxf(fmaxf(acc[i][0][r], acc[i][1][r]),
                             fmaxf(acc[i][2][r], acc[i][3][r]));
            m4 = fmaxf(m4, __shfl_xor(m4, 1));
            m4 = fmaxf(m4, __shfl_xor(m4, 2));
            m4 = fmaxf(m4, __shfl_xor(m4, 4));
            m4 = fmaxf(m4, __shfl_xor(m4, 8));
            if (cn == 0)
                redA[(nslice << 6) + wm + (i << 4) + (quad << 2) + r] = m4;
        }
    __syncthreads();
    float M[2][4];
    #pragma unroll
    for (int i = 0; i < 2; ++i)
        #pragma unroll
        for (int r = 0; r < 4; ++r) {
            int row = wm + (i << 4) + (quad << 2) + r;
            M[i][r] = fmaxf(fmaxf(redA[row], redA[64 + row]),
                            fmaxf(redA[128 + row], redA[192 + row]));
        }
    #pragma unroll
    for (int i = 0; i < 2; ++i)
        #pragma unroll
        for (int r = 0; r < 4; ++r) {
            float s4 = 0.f;
            #pragma unroll
            for (int j = 0; j < 4; ++j) {
                float e = __expf(acc[i][j][r] - M[i][r]);
                acc[i][j][r] = e;
                s4 += e;
            }
            s4 += __shfl_xor(s4, 1);
            s4 += __shfl_xor(s4, 2);
            s4 += __shfl_xor(s4, 4);
            s4 += __shfl_xor(s4, 8);
            if (cn == 0)
                redB[(nslice << 6) + wm + (i << 4) + (quad << 2) + r] = s4;
        }
    __syncthreads();
    #pragma unroll
    for (int i = 0; i < 2; ++i)
        #pragma unroll
        for (int r = 0; r < 4; ++r) {
            int row = wm + (i << 4) + (quad << 2) + r;
            float inv = 1.0f / (redB[row] + redB[64 + row] +
                                redB[128 + row] + redB[192 + row]);
            int s = s0 + row;
            #pragma unroll
            for (int j = 0; j < 4; ++j) {
                int n = wn + (j << 4) + cn;
                Pout[((size_t)b * 1028 + 2 + s) * 256 + n] =
                    __float2bfloat16(acc[i][j][r] * inv);
            }
        }
}

extern "C" void kernel_launch(void* const* d_in, const int* in_sizes, int n_in,
                              void* d_out, int out_size, void* d_ws, size_t ws_size,
                              hipStream_t stream) {
    const float* unary  = (const float*)d_in[1];
    const float* trans  = (const float*)d_in[3];
    const float* startT = (const float*)d_in[4];
    const float* endT   = (const float*)d_in[5];
    const int*   lens   = (const int*)d_in[6];

    char* ws = (char*)d_ws;
    __hip_bfloat16* Pa  = (__hip_bfloat16*)ws;                          // 16.8 MB
    __hip_bfloat16* Pb  = (__hip_bfloat16*)(ws + ((size_t)32 << 20));   // 16.8 MB
    __hip_bfloat16* WcT = (__hip_bfloat16*)(ws + ((size_t)64 << 20));   // 512 KB
    float* out = (float*)d_out;

    prep_softmax0<<<dim3(512), dim3(256), 0, stream>>>(unary, trans, lens, Pa, Pb, WcT);
    mfvi_iter_k<<<dim3(512), dim3(512), 0, stream>>>(Pa, WcT, unary, lens, startT, endT, Pb, nullptr, 0);
    mfvi_iter_k<<<dim3(512), dim3(512), 0, stream>>>(Pb, WcT, unary, lens, startT, endT, Pa, nullptr, 0);
    mfvi_iter_k<<<dim3(512), dim3(512), 0, stream>>>(Pa, WcT, unary, lens, startT, endT, nullptr, out, 1);
}